// Round 6
// baseline (530.297 us; speedup 1.0000x reference)
//
#include <hip/hip_runtime.h>
#include <hip/hip_bf16.h>
#include <cstdint>
#include <cstddef>

// MotionNet decoder: B=16384, STATE=524, IENC=256, ZD=32, H=256, E=5, HG=256
// Round 12 = round 10 with the macro-pasting compile error fixed:
// fA##SET##0.x pasted into the invalid token fA00.x ("0.x" is one pp-number
// token). Replaced with fA[2][2]/uA[2][2] arrays indexed by the literal SET
// macro arg (compile-time constant -> registers, no scratch).
// Round 10: prep_all was 111us @ 27% HBM — 2/3 of its traffic was the
// I->bf16 convert pass. Deleted: inet1 now reads I directly (runtime-dtype
// A path, reg-staged: load->f2bf->ds_write, T14 split with constant
// vmcnt(10)). Small GEMMs rebuilt as 64x256 tile (wave 32x128, acc[2][8],
// 3-buffer depth-2 counted-vmcnt) so A is read once (B L2-resident).
// prep_all: 8-wide h0 build, transposes only (~100 MB left). moe = r9 form.

#define BATCH 16384

typedef __attribute__((ext_vector_type(8))) short short8;  // 8 bf16 (4 VGPRs)
typedef __attribute__((ext_vector_type(4))) float f32x4;   // MFMA accumulator
typedef unsigned short u16;
typedef unsigned int u32;

typedef __attribute__((address_space(3))) void lds_t;
typedef __attribute__((address_space(1))) void gmem_t;

// async global->LDS DMA, 16 B/lane. LDS dest = wave-uniform base + lane*16.
__device__ __forceinline__ void gload16(const u16* g, u16* l) {
  __builtin_amdgcn_global_load_lds((gmem_t*)(u16*)g, (lds_t*)l, 16, 0, 0);
}

// raw workgroup barrier (no counter drain)
__device__ __forceinline__ void barrier_nodrain() {
  asm volatile("" ::: "memory");
  __builtin_amdgcn_s_barrier();
  asm volatile("" ::: "memory");
}
// barrier draining LDS ops only — vmcnt stays in flight
__device__ __forceinline__ void barrier_lds() {
  asm volatile("s_waitcnt lgkmcnt(0)" ::: "memory");
  __builtin_amdgcn_s_barrier();
  asm volatile("" ::: "memory");
}

__device__ __forceinline__ float bf2f(u16 u) {
  union { float f; u32 i; } v; v.i = ((u32)u) << 16; return v.f;
}
__device__ __forceinline__ u16 f2bf(float f) {
  union { float f; u32 i; } v; v.f = f;
  u32 x = v.i;
  return (u16)((x + 0x7fffu + ((x >> 16) & 1u)) >> 16);  // RNE
}
__device__ __forceinline__ u16 load_bf(const void* p, long i, int f32) {
  return f32 ? f2bf(((const float*)p)[i]) : ((const u16*)p)[i];
}
__device__ __forceinline__ float elu_f(float x) { return x > 0.f ? x : expm1f(x); }

// LDS tile layout (validated round 4): rows of 32 u16 (64 B); 16B chunk q of
// row r lives at chunk slot q^((r>>1)&3). Staging lane l covers global chunk
// (l&3)^((l>>3)&3) of row seg+(l>>2); 16B lands at base + l*16B = correct.
__device__ __forceinline__ int swz(int row, int q) { return q ^ ((row >> 1) & 3); }

// ---------------------------------------------------------------------------
// prep_all: fused {dtype detect (per-block), smallc canonicalize (block 0),
//   h0/h1c/h2c build (8 cols/item, 16B stores), all weight transposes}.
// h0 cols 556..831 zeroed (gat1 reads h0[:,0:576] before inet3 fills 556..).
// ---------------------------------------------------------------------------
struct TPSeg { long end; int K, N, Kp, Np; };

__global__ __launch_bounds__(256) void prep_all(
    const void* __restrict__ z, const void* __restrict__ p,
    int* __restrict__ flagp,
    u16* __restrict__ h0, u16* __restrict__ h1c, u16* __restrict__ h2c,
    const void* ib1, const void* ib2, const void* ib3,
    const void* gb1, const void* gb2, const void* gb3,
    const void* gw3, const void* bl1, const void* bl2, const void* bl3,
    u16* __restrict__ smallc,
    const void* s0, const void* s1, const void* s2, const void* s3,
    const void* s4, const void* s5, const void* s6, const void* s7,
    u16* d0, u16* d1, u16* d2, u16* d3, u16* d4, u16* d5, u16* d6, u16* d7)
{
  // ---- per-block dtype detection ----
  __shared__ int scnt[4];
  {
    u32 w = ((const u32*)z)[threadIdx.x];
    int e = (w >> 7) & 0xFF;
    unsigned long long m = __ballot(e >= 112 && e <= 142);
    if ((threadIdx.x & 63) == 0) scnt[threadIdx.x >> 6] = __popcll(m);
  }
  __syncthreads();
  const int f32 = (scnt[0] + scnt[1] + scnt[2] + scnt[3] < 128) ? 1 : 0;
  if (blockIdx.x == 0 && threadIdx.x == 0) *flagp = f32;

  // ---- block 0: small-tensor canonicalize ----
  if (blockIdx.x == 0) {
    for (long j = threadIdx.x; j < 7100; j += 256) {
      u16 v;
      if      (j < 256)  v = load_bf(ib1, j,        f32);
      else if (j < 512)  v = load_bf(ib2, j - 256,  f32);
      else if (j < 768)  v = load_bf(ib3, j - 512,  f32);
      else if (j < 1024) v = load_bf(gb1, j - 768,  f32);
      else if (j < 1152) v = load_bf(gb2, j - 1024, f32);
      else if (j < 1280) v = (j - 1152 < 5) ? load_bf(gb3, j - 1152, f32) : (u16)0;
      else if (j < 1920) v = load_bf(gw3, j - 1280, f32);
      else if (j < 3200) v = load_bf(bl1, j - 1920, f32);
      else if (j < 4480) v = load_bf(bl2, j - 3200, f32);
      else               v = load_bf(bl3, j - 4480, f32);
      smallc[j] = v;
    }
  }

  // seg4 (gw2t) padded to Np=256 (zero rows 128..255) for the 64x256 GEMM
  const TPSeg seg[8] = {
    {  524288, 2048, 256, 2048, 256 },
    {  589824,  256, 256,  256, 256 },
    {  655360,  256, 256,  256, 256 },
    {  802816,  556, 256,  576, 256 },
    {  868352,  256, 128,  256, 256 },
    { 1933312,  812, 256,  832, 256 },   // E=5
    { 2301952,  288, 256,  288, 256 },   // E=5
    { 3131392,  288, 524,  288, 576 },   // E=5
  };
  const void* const srcs[8] = { s0, s1, s2, s3, s4, s5, s6, s7 };
  u16* const dsts[8] = { d0, d1, d2, d3, d4, d5, d6, d7 };

  const long NP = (long)BATCH * 104;        // h-build items (8 cols each)
  const long NT = 3131392 / 4;              // transpose items (4 k each)
  const long total = NP + NT;
  const long stride = (long)gridDim.x * blockDim.x;

  for (long it = (long)blockIdx.x * 256 + threadIdx.x; it < total; it += stride) {
    if (it < NP) {
      const int b = (int)(it / 104);
      const int c = (int)(it % 104) * 8;
      uint4 w; w.x = 0; w.y = 0; w.z = 0; w.w = 0;
      if (c < 32) {
        if (f32) {
          const float4 f0 = *(const float4*)((const float*)z + (long)b * 32 + c);
          const float4 f1 = *(const float4*)((const float*)z + (long)b * 32 + c + 4);
          w.x = (u32)f2bf(f0.x) | ((u32)f2bf(f0.y) << 16);
          w.y = (u32)f2bf(f0.z) | ((u32)f2bf(f0.w) << 16);
          w.z = (u32)f2bf(f1.x) | ((u32)f2bf(f1.y) << 16);
          w.w = (u32)f2bf(f1.z) | ((u32)f2bf(f1.w) << 16);
        } else {
          w = *(const uint4*)((const u16*)z + (long)b * 32 + c);
        }
        *(uint4*)(h0 + (long)b * 832 + c) = w;
        *(uint4*)(h1c + (long)b * 288 + c) = w;
        *(uint4*)(h2c + (long)b * 288 + c) = w;
        continue;
      }
      if (c < 552) {
        const long pi = (long)b * 524 + (c - 32);
        if (f32) {
          const float4 f0 = *(const float4*)((const float*)p + pi);
          const float4 f1 = *(const float4*)((const float*)p + pi + 4);
          w.x = (u32)f2bf(f0.x) | ((u32)f2bf(f0.y) << 16);
          w.y = (u32)f2bf(f0.z) | ((u32)f2bf(f0.w) << 16);
          w.z = (u32)f2bf(f1.x) | ((u32)f2bf(f1.y) << 16);
          w.w = (u32)f2bf(f1.z) | ((u32)f2bf(f1.w) << 16);
        } else {
          const uint2 a0 = *(const uint2*)((const u16*)p + pi);
          const uint2 a1 = *(const uint2*)((const u16*)p + pi + 4);
          w.x = a0.x; w.y = a0.y; w.z = a1.x; w.w = a1.y;
        }
      } else if (c == 552) {
        const long pi = (long)b * 524 + 520;   // cols 552..555; 556..559 = 0
        if (f32) {
          const float4 f0 = *(const float4*)((const float*)p + pi);
          w.x = (u32)f2bf(f0.x) | ((u32)f2bf(f0.y) << 16);
          w.y = (u32)f2bf(f0.z) | ((u32)f2bf(f0.w) << 16);
        } else {
          const uint2 a0 = *(const uint2*)((const u16*)p + pi);
          w.x = a0.x; w.y = a0.y;
        }
      }
      *(uint4*)(h0 + (long)b * 832 + c) = w;
    } else {
      // ---- weight transpose, 4 consecutive k per item ----
      const long jd = (it - NP) * 4;
      int s = 0; long sbase = 0;
      while (jd >= seg[s].end) { sbase = seg[s].end; ++s; }
      const long jj = jd - sbase;
      const int Kp = seg[s].Kp, Np = seg[s].Np, Kk = seg[s].K, Nn = seg[s].N;
      const int k = (int)(jj % Kp);
      const long tt = jj / Kp;
      const int n = (int)(tt % Np);
      const int e = (int)(tt / Np);
      ushort4 v; v.x = 0; v.y = 0; v.z = 0; v.w = 0;
      if (k < Kk && n < Nn) {   // Kk,k both %4==0 -> uniform over the 4
        const long sb = (long)e * Kk * Nn + (long)k * Nn + n;
        v.x = load_bf(srcs[s], sb, f32);
        v.y = load_bf(srcs[s], sb + Nn, f32);
        v.z = load_bf(srcs[s], sb + 2 * (long)Nn, f32);
        v.w = load_bf(srcs[s], sb + 3 * (long)Nn, f32);
      }
      *(ushort4*)(dsts[s] + jj) = v;
    }
  }
}

// ---------------------------------------------------------------------------
// 64x256-tile GEMM: C = elu(A[M,K] @ W[K,N=256] + bias), W stored [N][K].
// 4 waves, wave tile 32x128 (a[2] x b[8] = 16 MFMA 16x16x32, acc[2][8]).
// A is reg-staged (supports runtime fp32/bf16 via a_mode: loads -> f2bf ->
// ds_write); B via global_load_lds DMA. 3 LDS buffers (60 KB, 2 blocks/CU),
// depth-2 pipeline, constant vmcnt(10):
//   barrier_lds -> {2 A-loads(t+2), 4 B-DMA(t+2)} -> vmcnt(10)
//   -> ds_write A(t+1) -> barrier -> ds_read + 16 MFMA (t)
// vmcnt(10) leaves {B(t+1):4, A(t+2):2, B(t+2):4} => A(t+1) + B(t) retired.
// blockIdx.y picks descriptor (horizontal fusion). K, nt even required.
// ---------------------------------------------------------------------------
struct GemmDesc {
  const void* A; const u16* Wt; const u16* bias; u16* C;
  int lda, ldw, ldc, col_off, K, n_store, a_mode;  // a_mode: 1 = dtype from flagp
};

__global__ __launch_bounds__(256, 2) void gemm64n(GemmDesc da, GemmDesc db,
                                                  const int* __restrict__ flagp)
{
  __shared__ __align__(16) u16 sAf[3 * 64 * 32];    // 4 KB per buffer
  __shared__ __align__(16) u16 sBf[3 * 256 * 32];   // 16 KB per buffer

  const GemmDesc d = blockIdx.y ? db : da;
  const int f32A = d.a_mode ? *flagp : 0;

  const int tid  = threadIdx.x;
  const int bm   = blockIdx.x;
  const int lane = tid & 63, wave = tid >> 6;
  const int wm = (wave & 1) * 32, wn = (wave >> 1) * 128;
  const int lrow = lane & 15, lq = lane >> 4;

  const int sq    = (lane & 3) ^ ((lane >> 3) & 3);
  const int srowA = 16 * wave + (lane >> 2);
  const size_t abase = (size_t)(bm * 64 + srowA) * d.lda + sq * 8;
  const float* Af = (const float*)d.A;
  const u16*   Ab = (const u16*)d.A;
  const int laOff = wave * 512;           // u16 offset inside an sA buffer

  const int ldw = d.ldw;
  const int srB = (lane >> 2);
  const u16* Wg0 = d.Wt + (size_t)(64 * wave +  0 + srB) * ldw + sq * 8;
  const u16* Wg1 = d.Wt + (size_t)(64 * wave + 16 + srB) * ldw + sq * 8;
  const u16* Wg2 = d.Wt + (size_t)(64 * wave + 32 + srB) * ldw + sq * 8;
  const u16* Wg3 = d.Wt + (size_t)(64 * wave + 48 + srB) * ldw + sq * 8;
  const int lb0 = wave * 2048, lb1 = lb0 + 512, lb2 = lb0 + 1024, lb3 = lb0 + 1536;

  float4 fA[2][2];   // [SET][half] — SET is always a literal at expansion
  uint2  uA[2][2];
  f32x4 acc[2][8] = {};
  const int nt = d.K / 32;   // even for all segments (64, 18, 8)

#define STAGE_LOAD(SET, k0_)                                          \
  { const int k0s = (k0_);                                            \
    if (f32A) {                                                       \
      fA[SET][0] = *(const float4*)(Af + abase + k0s);                \
      fA[SET][1] = *(const float4*)(Af + abase + k0s + 4);            \
    } else {                                                          \
      uA[SET][0] = *(const uint2*)(Ab + abase + k0s);                 \
      uA[SET][1] = *(const uint2*)(Ab + abase + k0s + 4);             \
    }                                                                 \
    u16* sBb = sBf + ((k0s >> 5) % 3) * 8192;                         \
    gload16(Wg0 + k0s, sBb + lb0);                                    \
    gload16(Wg1 + k0s, sBb + lb1);                                    \
    gload16(Wg2 + k0s, sBb + lb2);                                    \
    gload16(Wg3 + k0s, sBb + lb3); }

#define AWRITE(SET, bi_)                                              \
  { uint4 wv;                                                         \
    if (f32A) {                                                       \
      wv.x = (u32)f2bf(fA[SET][0].x) | ((u32)f2bf(fA[SET][0].y) << 16); \
      wv.y = (u32)f2bf(fA[SET][0].z) | ((u32)f2bf(fA[SET][0].w) << 16); \
      wv.z = (u32)f2bf(fA[SET][1].x) | ((u32)f2bf(fA[SET][1].y) << 16); \
      wv.w = (u32)f2bf(fA[SET][1].z) | ((u32)f2bf(fA[SET][1].w) << 16); \
    } else {                                                          \
      wv.x = uA[SET][0].x; wv.y = uA[SET][0].y;                       \
      wv.z = uA[SET][1].x; wv.w = uA[SET][1].y;                       \
    }                                                                 \
    *(uint4*)(sAf + (bi_) * 2048 + laOff + lane * 8) = wv; }

#define GSTEP(T, S, SO)                                               \
  { barrier_lds();                                                    \
    if ((T) + 2 < nt) STAGE_LOAD(S, ((T) + 2) * 32);                  \
    const int ahead = nt - 1 - (T);                                   \
    if (ahead >= 2)      asm volatile("s_waitcnt vmcnt(10)" ::: "memory"); \
    else if (ahead == 1) asm volatile("s_waitcnt vmcnt(4)"  ::: "memory"); \
    else                 asm volatile("s_waitcnt vmcnt(0)"  ::: "memory"); \
    if ((T) + 1 < nt) AWRITE(SO, ((T) + 1) % 3);                      \
    barrier_nodrain();                                                \
    const int cb = (T) % 3;                                           \
    short8 a[2], b[8];                                                \
    _Pragma("unroll")                                                 \
    for (int i = 0; i < 2; ++i) {                                     \
      const int r = wm + i * 16 + lrow;                               \
      a[i] = *(const short8*)(sAf + cb * 2048 + r * 32 + swz(r, lq) * 8); \
    }                                                                 \
    _Pragma("unroll")                                                 \
    for (int i = 0; i < 8; ++i) {                                     \
      const int r = wn + i * 16 + lrow;                               \
      b[i] = *(const short8*)(sBf + cb * 8192 + r * 32 + swz(r, lq) * 8); \
    }                                                                 \
    __builtin_amdgcn_s_setprio(1);                                    \
    _Pragma("unroll")                                                 \
    for (int mi = 0; mi < 2; ++mi)                                    \
      _Pragma("unroll")                                               \
      for (int ni = 0; ni < 8; ++ni)                                  \
        acc[mi][ni] = __builtin_amdgcn_mfma_f32_16x16x32_bf16(a[mi], b[ni], acc[mi][ni], 0, 0, 0); \
    __builtin_amdgcn_s_setprio(0); }

  // prologue: stage tiles 0 (set0) and 1 (set1); write A(0)
  STAGE_LOAD(0, 0)
  STAGE_LOAD(1, 32)
  asm volatile("s_waitcnt vmcnt(10)" ::: "memory");   // A(0) loads retired
  AWRITE(0, 0)

  for (int t = 0; t < nt; t += 2) {
    GSTEP(t, 0, 1)
    GSTEP(t + 1, 1, 0)
  }
#undef GSTEP
#undef AWRITE
#undef STAGE_LOAD

#pragma unroll
  for (int ni = 0; ni < 8; ++ni) {
    const int col = wn + ni * 16 + lrow;
    if (col < d.n_store) {
      const float bv = bf2f(d.bias[col]);
#pragma unroll
      for (int mi = 0; mi < 2; ++mi) {
#pragma unroll
        for (int r = 0; r < 4; ++r) {
          const int row = bm * 64 + wm + mi * 16 + lq * 4 + r;
          float v = acc[mi][ni][r] + bv;
          v = elu_f(v);
          d.C[(size_t)row * d.ldc + d.col_off + col] = f2bf(v);
        }
      }
    }
  }
}

// ---------------------------------------------------------------------------
// MoE GEMM (r9 form, validated): out = act( sum_e om[b,e]*((A@W_e)+b_e) )
// 256 thr, block 128x64, wave tile 64x32, acc[5][4][2]; depth-1 counted-vmcnt
// (2 buffers, 56KB, 2 blocks/CU). Gating layer-3 + softmax fused in prologue.
// ---------------------------------------------------------------------------
template<bool ELU>
__global__ __launch_bounds__(256, 2) void moe_gemm(
    const u16* __restrict__ A, int lda,
    const u16* __restrict__ Wt, int ldw, long wstride_e,
    const u16* __restrict__ bias, int bias_n,
    const u16* __restrict__ g2, const u16* __restrict__ gw3c,
    const u16* __restrict__ gb3c,
    void* __restrict__ C, int ldc, int col_off, int n_store, int K,
    const int* __restrict__ flagp, int is_final)
{
  __shared__ __align__(16) u16 sA[2][128 * 32];     // 8 KB each
  __shared__ __align__(16) u16 sW[2][5 * 64 * 32];  // 20 KB each
  __shared__ float som[128 * 5];
  __shared__ float sbias[5][64];
  __shared__ float sgw[128 * 5];
  __shared__ float sgb[5];

  const int tid  = threadIdx.x;
  const int bm   = blockIdx.x, bn = blockIdx.y;
  const int lane = tid & 63, wave = tid >> 6;
  const int wm = (wave & 1) * 64, wn = (wave >> 1) * 32;
  const int lrow = lane & 15, lq = lane >> 4;
  const int f32out = is_final ? *flagp : 0;

  const int sq = (lane & 3) ^ ((lane >> 3) & 3);
  const int srowA = 32 * wave + (lane >> 2);
  const int srowW = 16 * wave + (lane >> 2);
  const u16* Ag = A  + (size_t)(bm * 128 + srowA) * lda + sq * 8;
  const u16* Wg = Wt + (size_t)(bn * 64 + srowW) * ldw + sq * 8;
  const int laOff = wave * 1024;    // 32 rows * 32 u16
  const int lWoff = wave * 512;     // 16 rows * 32 u16

  auto stage = [&](int buf, int k0) {
    gload16(Ag + k0, sA[buf] + laOff);
    gload16(Ag + (size_t)16 * lda + k0, sA[buf] + laOff + 512);
#pragma unroll
    for (int e = 0; e < 5; ++e)
      gload16(Wg + e * wstride_e + k0, sW[buf] + e * 2048 + lWoff);
  };

  f32x4 acc[5][4][2] = {};
  const int nt = K / 32;

  // ---- prologue: tile-0 DMAs in flight while omega is built in-block ----
  stage(0, 0);
  for (int t2 = tid; t2 < 960; t2 += 256) {   // 640 sgw + 320 sbias
    if (t2 < 640) {
      sgw[t2] = bf2f(gw3c[t2]);
    } else {
      const int j = t2 - 640;
      const int e = j >> 6, c = j & 63;
      const int col = bn * 64 + c;
      sbias[e][c] = (col < bias_n) ? bf2f(bias[(size_t)e * bias_n + col]) : 0.f;
    }
  }
  if (tid < 5) sgb[tid] = bf2f(gb3c[tid]);
  barrier_lds();                              // sgw/sgb visible; DMAs still fly
  if (tid < 128) {
    const u16* gr = g2 + (size_t)(bm * 128 + tid) * 128;
    float t[5];
#pragma unroll
    for (int e = 0; e < 5; ++e) t[e] = sgb[e];
    for (int k = 0; k < 128; k += 2) {
      const u32 gp = *(const u32*)(gr + k);
      const float x0 = bf2f((u16)(gp & 0xffffu));
      const float x1 = bf2f((u16)(gp >> 16));
#pragma unroll
      for (int e = 0; e < 5; ++e)
        t[e] += x0 * sgw[k * 5 + e] + x1 * sgw[(k + 1) * 5 + e];
    }
    float m = t[0];
#pragma unroll
    for (int e = 1; e < 5; ++e) m = fmaxf(m, t[e]);
    float ssum = 0.f;
#pragma unroll
    for (int e = 0; e < 5; ++e) { t[e] = expf(t[e] - m); ssum += t[e]; }
    const float inv = 1.f / ssum;
#pragma unroll
    for (int e = 0; e < 5; ++e) som[tid * 5 + e] = t[e] * inv;
  }

  for (int t = 0; t < nt; ++t) {
    const int cur = t & 1;
    barrier_nodrain();                   // WAR: buf[cur^1] free / syncs prologue
    if (t + 1 < nt) {
      stage(cur ^ 1, (t + 1) * 32);
      asm volatile("s_waitcnt vmcnt(7)" ::: "memory");   // tile t landed
    } else {
      asm volatile("s_waitcnt vmcnt(0)" ::: "memory");
    }
    barrier_nodrain();                   // all waves' tile-t DMAs visible

    short8 a[4];
#pragma unroll
    for (int i = 0; i < 4; ++i) {
      const int r = wm + i * 16 + lrow;
      a[i] = *(const short8*)(sA[cur] + r * 32 + swz(r, lq) * 8);
    }
    const int rb0 = wn + lrow, rb1 = rb0 + 16;
    const int ob0 = rb0 * 32 + swz(rb0, lq) * 8;
    const int ob1 = rb1 * 32 + swz(rb1, lq) * 8;
    __builtin_amdgcn_s_setprio(1);
#pragma unroll
    for (int e = 0; e < 5; ++e) {
      short8 b0 = *(const short8*)(sW[cur] + e * 2048 + ob0);
      short8 b1 = *(const short8*)(sW[cur] + e * 2048 + ob1);
#pragma unroll
      for (int mi = 0; mi < 4; ++mi) {
        acc[e][mi][0] = __builtin_amdgcn_mfma_f32_16x16x32_bf16(a[mi], b0, acc[e][mi][0], 0, 0, 0);
        acc[e][mi][1] = __builtin_amdgcn_mfma_f32_16x16x32_bf16(a[mi], b1, acc[e][mi][1], 0, 0, 0);
      }
    }
    __builtin_amdgcn_s_setprio(0);
  }

#pragma unroll
  for (int mi = 0; mi < 4; ++mi) {
#pragma unroll
    for (int r = 0; r < 4; ++r) {
      const int rl = wm + mi * 16 + lq * 4 + r;       // row in block tile
      const int row = bm * 128 + rl;
      float om[5];
#pragma unroll
      for (int e = 0; e < 5; ++e) om[e] = som[rl * 5 + e];
#pragma unroll
      for (int ni = 0; ni < 2; ++ni) {
        const int c = wn + ni * 16 + lrow;            // col in block tile
        const int col = bn * 64 + c;
        if (col < n_store) {
          float v = 0.f;
#pragma unroll
          for (int e = 0; e < 5; ++e) v += om[e] * (acc[e][mi][ni][r] + sbias[e][c]);
          if (ELU) v = elu_f(v);
          const size_t idx = (size_t)row * ldc + col_off + col;
          if (f32out) ((float*)C)[idx] = v;
          else        ((u16*)C)[idx]   = f2bf(v);
        }
      }
    }
  }
}

// ---------------------------------------------------------------------------
extern "C" void kernel_launch(void* const* d_in, const int* in_sizes, int n_in,
                              void* d_out, int out_size, void* d_ws, size_t ws_size,
                              hipStream_t stream)
{
  const void* z    = d_in[0];
  const void* pprev= d_in[1];
  const void* I    = d_in[2];
  const void* gw1  = d_in[3];
  const void* gb1  = d_in[4];
  const void* gw2  = d_in[5];
  const void* gb2  = d_in[6];
  const void* gw3  = d_in[7];
  const void* gb3  = d_in[8];
  const void* iw1  = d_in[9];
  const void* ib1  = d_in[10];
  const void* iw2  = d_in[11];
  const void* ib2  = d_in[12];
  const void* iw3  = d_in[13];
  const void* ib3  = d_in[14];
  const void* wl1  = d_in[15];
  const void* bl1  = d_in[16];
  const void* wl2  = d_in[17];
  const void* bl2  = d_in[18];
  const void* wl3  = d_in[19];
  const void* bl3  = d_in[20];

  char* base = (char*)d_ws;
  size_t off = 0;
  auto alloc = [&](size_t bytes) -> void* {
    void* p = base + off;
    off = (off + bytes + 255) & ~(size_t)255;
    return p;
  };

  const size_t B = BATCH;
  int* flagp   = (int*)alloc(256);
  u16* h0      = (u16*)alloc(B * 832 * 2);   // [z | p_prev | ienc | pad0]
  u16* h1c     = (u16*)alloc(B * 288 * 2);   // [z | h1]
  u16* h2c     = (u16*)alloc(B * 288 * 2);   // [z | h2]
  u16* i1      = (u16*)alloc(B * 256 * 2);
  u16* i2      = (u16*)alloc(B * 256 * 2);
  u16* g1      = (u16*)alloc(B * 256 * 2);
  u16* g2      = (u16*)alloc(B * 128 * 2);
  u16* smallc  = (u16*)alloc(7100 * 2);
  u16* iw1t = (u16*)alloc((size_t)256 * 2048 * 2);
  u16* iw2t = (u16*)alloc((size_t)256 * 256 * 2);
  u16* iw3t = (u16*)alloc((size_t)256 * 256 * 2);
  u16* gw1t = (u16*)alloc((size_t)256 * 576 * 2);
  u16* gw2t = (u16*)alloc((size_t)256 * 256 * 2);   // padded rows 128..255 = 0
  u16* wl1t = (u16*)alloc((size_t)5 * 256 * 832 * 2);
  u16* wl2t = (u16*)alloc((size_t)5 * 256 * 288 * 2);
  u16* wl3t = (u16*)alloc((size_t)5 * 576 * 288 * 2);
  (void)in_sizes; (void)n_in; (void)out_size; (void)ws_size;

  u16* ib1c = smallc + 0,   *ib2c = smallc + 256, *ib3c = smallc + 512;
  u16* gb1c = smallc + 768, *gb2c = smallc + 1024, *gb3c = smallc + 1152;
  u16* gw3c = smallc + 1280;
  u16* bl1c = smallc + 1920, *bl2c = smallc + 3200, *bl3c = smallc + 4480;

  // ---- fused prep: dtype detect + canonicalize + h-build + transpose ----
  prep_all<<<2048, 256, 0, stream>>>(z, pprev, flagp, h0, h1c, h2c,
      ib1, ib2, ib3, gb1, gb2, gb3, gw3, bl1, bl2, bl3, smallc,
      iw1, iw2, iw3, gw1, gw2, wl1, wl2, wl3,
      iw1t, iw2t, iw3t, gw1t, gw2t, wl1t, wl2t, wl3t);

  // ---- small GEMMs, 64x256 tile: INet chain || gating chain ----
  GemmDesc inet1 = { I,   iw1t, ib1c, i1, 2048, 2048, 256, 0,   2048, 256, 1 };
  GemmDesc gat1  = { h0,  gw1t, gb1c, g1,  832,  576, 256, 0,    576, 256, 0 };
  GemmDesc inet2 = { i1,  iw2t, ib2c, i2,  256,  256, 256, 0,    256, 256, 0 };
  GemmDesc gat2  = { g1,  gw2t, gb2c, g2,  256,  256, 128, 0,    256, 128, 0 };
  GemmDesc inet3 = { i2,  iw3t, ib3c, h0,  256,  256, 832, 556,  256, 256, 0 };

  gemm64n<<<dim3(BATCH/64, 2), 256, 0, stream>>>(inet1, gat1, flagp);
  gemm64n<<<dim3(BATCH/64, 2), 256, 0, stream>>>(inet2, gat2, flagp);
  gemm64n<<<dim3(BATCH/64, 1), 256, 0, stream>>>(inet3, inet3, flagp);

  // ---- MoE layers (block 128x64, depth-1 counted-vmcnt, omega in-block) ----
  moe_gemm<true><<<dim3(BATCH/128, 4), 256, 0, stream>>>(
      h0, 832, wl1t, 832, (long)256 * 832, bl1c, 256, g2, gw3c, gb3c,
      h1c, 288, 32, 256, 832, flagp, 0);
  moe_gemm<true><<<dim3(BATCH/128, 4), 256, 0, stream>>>(
      h1c, 288, wl2t, 288, (long)256 * 288, bl2c, 256, g2, gw3c, gb3c,
      h2c, 288, 32, 256, 288, flagp, 0);
  moe_gemm<false><<<dim3(BATCH/128, 9), 256, 0, stream>>>(
      h2c, 288, wl3t, 288, (long)576 * 288, bl3c, 524, g2, gw3c, gb3c,
      d_out, 524, 0, 524, 288, flagp, 1);
}

// Round 8
// 517.145 us; speedup vs baseline: 1.0254x; 1.0254x over previous
//
#include <hip/hip_runtime.h>
#include <hip/hip_bf16.h>
#include <cstdint>
#include <cstddef>

// MotionNet decoder: B=16384, STATE=524, IENC=256, ZD=32, H=256, E=5, HG=256
// Round 14 = round 13 resubmission (r13 died at the container/acquire layer
// before pytest ran — r10/r11 precedent shows compile errors surface through
// pytest, so this was infra; diff re-audited line-level anyway: no macros,
// matched aggregate inits, uniform barriers, balanced vmcnt, in-bounds).
// Round 13: r12 showed the 64x256 gemm64n REGRESSED small GEMMs (114us @
// 7.4% MFMA, 15% occ). This round:
//  - small GEMMs back to r9-validated gemm64m (64x128, 3-buffer depth-2 DMA,
//    vmcnt(6/3/0)) with __launch_bounds__(256,4): 36KB LDS -> 4 blocks/CU.
//  - I read path: device-side select. bf16 storage -> inet1 DMAs from I
//    directly; f32 -> prep_all converts I->Ibf (branch costs 0 when bf16).
//  - prep_all keeps the r10 8-wide h-build; moe = r9/r12 validated form.

#define BATCH 16384

typedef __attribute__((ext_vector_type(8))) short short8;  // 8 bf16 (4 VGPRs)
typedef __attribute__((ext_vector_type(4))) float f32x4;   // MFMA accumulator
typedef unsigned short u16;
typedef unsigned int u32;

typedef __attribute__((address_space(3))) void lds_t;
typedef __attribute__((address_space(1))) void gmem_t;

// async global->LDS DMA, 16 B/lane. LDS dest = wave-uniform base + lane*16.
__device__ __forceinline__ void gload16(const u16* g, u16* l) {
  __builtin_amdgcn_global_load_lds((gmem_t*)(u16*)g, (lds_t*)l, 16, 0, 0);
}

// raw workgroup barrier (no counter drain)
__device__ __forceinline__ void barrier_nodrain() {
  asm volatile("" ::: "memory");
  __builtin_amdgcn_s_barrier();
  asm volatile("" ::: "memory");
}
// barrier draining LDS ops only — vmcnt stays in flight
__device__ __forceinline__ void barrier_lds() {
  asm volatile("s_waitcnt lgkmcnt(0)" ::: "memory");
  __builtin_amdgcn_s_barrier();
  asm volatile("" ::: "memory");
}

__device__ __forceinline__ float bf2f(u16 u) {
  union { float f; u32 i; } v; v.i = ((u32)u) << 16; return v.f;
}
__device__ __forceinline__ u16 f2bf(float f) {
  union { float f; u32 i; } v; v.f = f;
  u32 x = v.i;
  return (u16)((x + 0x7fffu + ((x >> 16) & 1u)) >> 16);  // RNE
}
__device__ __forceinline__ u16 load_bf(const void* p, long i, int f32) {
  return f32 ? f2bf(((const float*)p)[i]) : ((const u16*)p)[i];
}
__device__ __forceinline__ float elu_f(float x) { return x > 0.f ? x : expm1f(x); }

// LDS tile layout (validated round 4): rows of 32 u16 (64 B); 16B chunk q of
// row r lives at chunk slot q^((r>>1)&3). Staging lane l covers global chunk
// (l&3)^((l>>3)&3) of row seg+(l>>2); 16B lands at base + l*16B = correct.
__device__ __forceinline__ int swz(int row, int q) { return q ^ ((row >> 1) & 3); }

// ---------------------------------------------------------------------------
// prep_all: fused {dtype detect (per-block), smallc canonicalize (block 0),
//   I->bf16 convert (ONLY when f32 storage), h0/h1c/h2c build (8 cols/item),
//   all weight transposes}. h0 cols 556..831 zeroed (gat1 reads h0[:,0:576]
//   before inet3 fills 556..).
// ---------------------------------------------------------------------------
struct TPSeg { long end; int K, N, Kp, Np; };

__global__ __launch_bounds__(256) void prep_all(
    const void* __restrict__ z, const void* __restrict__ p,
    const void* __restrict__ I, int* __restrict__ flagp,
    u16* __restrict__ h0, u16* __restrict__ h1c, u16* __restrict__ h2c,
    u16* __restrict__ Ibf,
    const void* ib1, const void* ib2, const void* ib3,
    const void* gb1, const void* gb2, const void* gb3,
    const void* gw3, const void* bl1, const void* bl2, const void* bl3,
    u16* __restrict__ smallc,
    const void* s0, const void* s1, const void* s2, const void* s3,
    const void* s4, const void* s5, const void* s6, const void* s7,
    u16* d0, u16* d1, u16* d2, u16* d3, u16* d4, u16* d5, u16* d6, u16* d7)
{
  // ---- per-block dtype detection ----
  __shared__ int scnt[4];
  {
    u32 w = ((const u32*)z)[threadIdx.x];
    int e = (w >> 7) & 0xFF;
    unsigned long long m = __ballot(e >= 112 && e <= 142);
    if ((threadIdx.x & 63) == 0) scnt[threadIdx.x >> 6] = __popcll(m);
  }
  __syncthreads();
  const int f32 = (scnt[0] + scnt[1] + scnt[2] + scnt[3] < 128) ? 1 : 0;
  if (blockIdx.x == 0 && threadIdx.x == 0) *flagp = f32;

  // ---- block 0: small-tensor canonicalize ----
  if (blockIdx.x == 0) {
    for (long j = threadIdx.x; j < 7100; j += 256) {
      u16 v;
      if      (j < 256)  v = load_bf(ib1, j,        f32);
      else if (j < 512)  v = load_bf(ib2, j - 256,  f32);
      else if (j < 768)  v = load_bf(ib3, j - 512,  f32);
      else if (j < 1024) v = load_bf(gb1, j - 768,  f32);
      else if (j < 1152) v = load_bf(gb2, j - 1024, f32);
      else if (j < 1280) v = (j - 1152 < 5) ? load_bf(gb3, j - 1152, f32) : (u16)0;
      else if (j < 1920) v = load_bf(gw3, j - 1280, f32);
      else if (j < 3200) v = load_bf(bl1, j - 1920, f32);
      else if (j < 4480) v = load_bf(bl2, j - 3200, f32);
      else               v = load_bf(bl3, j - 4480, f32);
      smallc[j] = v;
    }
  }

  const TPSeg seg[8] = {
    {  524288, 2048, 256, 2048, 256 },
    {  589824,  256, 256,  256, 256 },
    {  655360,  256, 256,  256, 256 },
    {  802816,  556, 256,  576, 256 },
    {  835584,  256, 128,  256, 128 },
    { 1900544,  812, 256,  832, 256 },   // E=5
    { 2269184,  288, 256,  288, 256 },   // E=5
    { 3098624,  288, 524,  288, 576 },   // E=5
  };
  const void* const srcs[8] = { s0, s1, s2, s3, s4, s5, s6, s7 };
  u16* const dsts[8] = { d0, d1, d2, d3, d4, d5, d6, d7 };

  const long NC = (long)BATCH * 2048 / 8;   // convert items (f32 only)
  const long NP = (long)BATCH * 104;        // h-build items (8 cols each)
  const long NT = 3098624 / 4;              // transpose items (4 k each)
  const long total = NC + NP + NT;
  const long stride = (long)gridDim.x * blockDim.x;

  for (long it = (long)blockIdx.x * 256 + threadIdx.x; it < total; it += stride) {
    if (it < NC) {
      if (f32) {   // bf16 storage: inet1 reads I directly, skip entirely
        const long t = it;
        const float4* src = (const float4*)I;
        float4 a = src[t * 2], b = src[t * 2 + 1];
        union { u16 r[8]; uint4 v; } u;
        u.r[0] = f2bf(a.x); u.r[1] = f2bf(a.y); u.r[2] = f2bf(a.z); u.r[3] = f2bf(a.w);
        u.r[4] = f2bf(b.x); u.r[5] = f2bf(b.y); u.r[6] = f2bf(b.z); u.r[7] = f2bf(b.w);
        *(uint4*)(Ibf + t * 8) = u.v;
      }
    } else if (it < NC + NP) {
      const long j = it - NC;
      const int b = (int)(j / 104);
      const int c = (int)(j % 104) * 8;
      uint4 w; w.x = 0; w.y = 0; w.z = 0; w.w = 0;
      if (c < 32) {
        if (f32) {
          const float4 f0 = *(const float4*)((const float*)z + (long)b * 32 + c);
          const float4 f1 = *(const float4*)((const float*)z + (long)b * 32 + c + 4);
          w.x = (u32)f2bf(f0.x) | ((u32)f2bf(f0.y) << 16);
          w.y = (u32)f2bf(f0.z) | ((u32)f2bf(f0.w) << 16);
          w.z = (u32)f2bf(f1.x) | ((u32)f2bf(f1.y) << 16);
          w.w = (u32)f2bf(f1.z) | ((u32)f2bf(f1.w) << 16);
        } else {
          w = *(const uint4*)((const u16*)z + (long)b * 32 + c);
        }
        *(uint4*)(h0 + (long)b * 832 + c) = w;
        *(uint4*)(h1c + (long)b * 288 + c) = w;
        *(uint4*)(h2c + (long)b * 288 + c) = w;
        continue;
      }
      if (c < 552) {
        const long pi = (long)b * 524 + (c - 32);
        if (f32) {
          const float4 f0 = *(const float4*)((const float*)p + pi);
          const float4 f1 = *(const float4*)((const float*)p + pi + 4);
          w.x = (u32)f2bf(f0.x) | ((u32)f2bf(f0.y) << 16);
          w.y = (u32)f2bf(f0.z) | ((u32)f2bf(f0.w) << 16);
          w.z = (u32)f2bf(f1.x) | ((u32)f2bf(f1.y) << 16);
          w.w = (u32)f2bf(f1.z) | ((u32)f2bf(f1.w) << 16);
        } else {
          const uint2 a0 = *(const uint2*)((const u16*)p + pi);
          const uint2 a1 = *(const uint2*)((const u16*)p + pi + 4);
          w.x = a0.x; w.y = a0.y; w.z = a1.x; w.w = a1.y;
        }
      } else if (c == 552) {
        const long pi = (long)b * 524 + 520;   // cols 552..555; 556..559 = 0
        if (f32) {
          const float4 f0 = *(const float4*)((const float*)p + pi);
          w.x = (u32)f2bf(f0.x) | ((u32)f2bf(f0.y) << 16);
          w.y = (u32)f2bf(f0.z) | ((u32)f2bf(f0.w) << 16);
        } else {
          const uint2 a0 = *(const uint2*)((const u16*)p + pi);
          w.x = a0.x; w.y = a0.y;
        }
      }
      *(uint4*)(h0 + (long)b * 832 + c) = w;
    } else {
      // ---- weight transpose, 4 consecutive k per item ----
      const long jd = (it - NC - NP) * 4;
      int s = 0; long sbase = 0;
      while (jd >= seg[s].end) { sbase = seg[s].end; ++s; }
      const long jj = jd - sbase;
      const int Kp = seg[s].Kp, Np = seg[s].Np, Kk = seg[s].K, Nn = seg[s].N;
      const int k = (int)(jj % Kp);
      const long tt = jj / Kp;
      const int n = (int)(tt % Np);
      const int e = (int)(tt / Np);
      ushort4 v; v.x = 0; v.y = 0; v.z = 0; v.w = 0;
      if (k < Kk && n < Nn) {   // Kk,k both %4==0 -> uniform over the 4
        const long sb = (long)e * Kk * Nn + (long)k * Nn + n;
        v.x = load_bf(srcs[s], sb, f32);
        v.y = load_bf(srcs[s], sb + Nn, f32);
        v.z = load_bf(srcs[s], sb + 2 * (long)Nn, f32);
        v.w = load_bf(srcs[s], sb + 3 * (long)Nn, f32);
      }
      *(ushort4*)(dsts[s] + jj) = v;
    }
  }
}

// ---------------------------------------------------------------------------
// Multi-segment GEMM (r9-validated form): C = elu(A @ W + bias), W [N][K].
// Block 64x128, 4 waves 2(M)x2(N), wave tile 32x64 = 2x4 MFMA 16x16x32.
// 3 LDS buffers (36 KB), depth-2 counted-vmcnt pipeline:
//   barrier -> stage(t+2) -> s_waitcnt vmcnt(6) -> barrier -> ds_read+MFMA
// __launch_bounds__(256,4): 36KB LDS + ~88 VGPR -> 4 blocks/CU (16 waves).
// A pointer selected on-device: a_mode && *flagp -> Aalt (prep-converted).
// ---------------------------------------------------------------------------
struct GemmDesc {
  const u16* A; const u16* Aalt; const u16* Wt; const u16* bias; u16* C;
  int lda, ldw, ldc, col_off, K, ny, a_mode;
};

__global__ __launch_bounds__(256, 4) void gemm64m(GemmDesc da, GemmDesc db,
                                                  const int* __restrict__ flagp)
{
  __shared__ __align__(16) u16 sA[3][64 * 32];    // 4 KB each
  __shared__ __align__(16) u16 sB[3][128 * 32];   // 8 KB each

  int bn = blockIdx.y;
  GemmDesc d;
  if (bn < da.ny) { d = da; } else { bn -= da.ny; d = db; }
  const u16* Abase = (d.a_mode && *flagp) ? d.Aalt : d.A;

  const int tid  = threadIdx.x;
  const int bm   = blockIdx.x;
  const int lane = tid & 63, wave = tid >> 6;
  const int wm = (wave & 1) * 32, wn = (wave >> 1) * 64;
  const int lrow = lane & 15, lq = lane >> 4;

  // staging: A rows 16/wave (1 DMA), B rows 32/wave (2 DMAs)
  const int sq    = (lane & 3) ^ ((lane >> 3) & 3);
  const int srowA = 16 * wave + (lane >> 2);
  const int srowB = 32 * wave + (lane >> 2);
  const u16* Ag = Abase + (size_t)(bm * 64  + srowA) * d.lda + sq * 8;
  const u16* Wg = d.Wt  + (size_t)(bn * 128 + srowB) * d.ldw + sq * 8;
  const int laOff = wave * 512;    // 16 rows * 32 u16
  const int lbOff = wave * 1024;   // 32 rows * 32 u16
  const int ldw = d.ldw;

  f32x4 acc[2][4] = {};
  const int nt = d.K / 32;

  // prologue: stage tiles 0 and 1 (no drain — loop's vmcnt covers)
  gload16(Ag, sA[0] + laOff);
  gload16(Wg, sB[0] + lbOff);
  gload16(Wg + (size_t)16 * ldw, sB[0] + lbOff + 512);
  gload16(Ag + 32, sA[1] + laOff);
  gload16(Wg + 32, sB[1] + lbOff);
  gload16(Wg + (size_t)16 * ldw + 32, sB[1] + lbOff + 512);

  for (int t = 0; t < nt; ++t) {
    const int cur = t % 3;
    barrier_nodrain();                       // WAR: slot (t+2)%3 free
    if (t + 2 < nt) {
      const int nb = (t + 2) % 3;
      const int k0 = (t + 2) * 32;
      gload16(Ag + k0, sA[nb] + laOff);
      gload16(Wg + k0, sB[nb] + lbOff);
      gload16(Wg + (size_t)16 * ldw + k0, sB[nb] + lbOff + 512);
    }
    const int ahead = nt - 1 - t;
    if (ahead >= 2)      asm volatile("s_waitcnt vmcnt(6)" ::: "memory");
    else if (ahead == 1) asm volatile("s_waitcnt vmcnt(3)" ::: "memory");
    else                 asm volatile("s_waitcnt vmcnt(0)" ::: "memory");
    barrier_nodrain();                       // all waves' tile-t DMAs visible

    short8 a[2], b[4];
#pragma unroll
    for (int i = 0; i < 2; ++i) {
      const int r = wm + i * 16 + lrow;
      a[i] = *(const short8*)(sA[cur] + r * 32 + swz(r, lq) * 8);
    }
#pragma unroll
    for (int i = 0; i < 4; ++i) {
      const int r = wn + i * 16 + lrow;
      b[i] = *(const short8*)(sB[cur] + r * 32 + swz(r, lq) * 8);
    }

    __builtin_amdgcn_s_setprio(1);
#pragma unroll
    for (int mi = 0; mi < 2; ++mi)
#pragma unroll
      for (int ni = 0; ni < 4; ++ni)
        acc[mi][ni] = __builtin_amdgcn_mfma_f32_16x16x32_bf16(a[mi], b[ni], acc[mi][ni], 0, 0, 0);
    __builtin_amdgcn_s_setprio(0);
  }

#pragma unroll
  for (int ni = 0; ni < 4; ++ni) {
    const int col = bn * 128 + wn + ni * 16 + lrow;
    const float bv = bf2f(d.bias[col]);
#pragma unroll
    for (int mi = 0; mi < 2; ++mi) {
#pragma unroll
      for (int r = 0; r < 4; ++r) {
        const int row = bm * 64 + wm + mi * 16 + lq * 4 + r;
        float v = acc[mi][ni][r] + bv;
        v = elu_f(v);
        d.C[(size_t)row * d.ldc + d.col_off + col] = f2bf(v);
      }
    }
  }
}

// ---------------------------------------------------------------------------
// MoE GEMM (r9 form, validated): out = act( sum_e om[b,e]*((A@W_e)+b_e) )
// 256 thr, block 128x64, wave tile 64x32, acc[5][4][2]; depth-1 counted-vmcnt
// (2 buffers, 56KB, 2 blocks/CU). Gating layer-3 + softmax fused in prologue.
// ---------------------------------------------------------------------------
template<bool ELU>
__global__ __launch_bounds__(256, 2) void moe_gemm(
    const u16* __restrict__ A, int lda,
    const u16* __restrict__ Wt, int ldw, long wstride_e,
    const u16* __restrict__ bias, int bias_n,
    const u16* __restrict__ g2, const u16* __restrict__ gw3c,
    const u16* __restrict__ gb3c,
    void* __restrict__ C, int ldc, int col_off, int n_store, int K,
    const int* __restrict__ flagp, int is_final)
{
  __shared__ __align__(16) u16 sA[2][128 * 32];     // 8 KB each
  __shared__ __align__(16) u16 sW[2][5 * 64 * 32];  // 20 KB each
  __shared__ float som[128 * 5];
  __shared__ float sbias[5][64];
  __shared__ float sgw[128 * 5];
  __shared__ float sgb[5];

  const int tid  = threadIdx.x;
  const int bm   = blockIdx.x, bn = blockIdx.y;
  const int lane = tid & 63, wave = tid >> 6;
  const int wm = (wave & 1) * 64, wn = (wave >> 1) * 32;
  const int lrow = lane & 15, lq = lane >> 4;
  const int f32out = is_final ? *flagp : 0;

  const int sq = (lane & 3) ^ ((lane >> 3) & 3);
  const int srowA = 32 * wave + (lane >> 2);
  const int srowW = 16 * wave + (lane >> 2);
  const u16* Ag = A  + (size_t)(bm * 128 + srowA) * lda + sq * 8;
  const u16* Wg = Wt + (size_t)(bn * 64 + srowW) * ldw + sq * 8;
  const int laOff = wave * 1024;    // 32 rows * 32 u16
  const int lWoff = wave * 512;     // 16 rows * 32 u16

  auto stage = [&](int buf, int k0) {
    gload16(Ag + k0, sA[buf] + laOff);
    gload16(Ag + (size_t)16 * lda + k0, sA[buf] + laOff + 512);
#pragma unroll
    for (int e = 0; e < 5; ++e)
      gload16(Wg + e * wstride_e + k0, sW[buf] + e * 2048 + lWoff);
  };

  f32x4 acc[5][4][2] = {};
  const int nt = K / 32;

  // ---- prologue: tile-0 DMAs in flight while omega is built in-block ----
  stage(0, 0);
  for (int t2 = tid; t2 < 960; t2 += 256) {   // 640 sgw + 320 sbias
    if (t2 < 640) {
      sgw[t2] = bf2f(gw3c[t2]);
    } else {
      const int j = t2 - 640;
      const int e = j >> 6, c = j & 63;
      const int col = bn * 64 + c;
      sbias[e][c] = (col < bias_n) ? bf2f(bias[(size_t)e * bias_n + col]) : 0.f;
    }
  }
  if (tid < 5) sgb[tid] = bf2f(gb3c[tid]);
  barrier_lds();                              // sgw/sgb visible; DMAs still fly
  if (tid < 128) {
    const u16* gr = g2 + (size_t)(bm * 128 + tid) * 128;
    float t[5];
#pragma unroll
    for (int e = 0; e < 5; ++e) t[e] = sgb[e];
    for (int k = 0; k < 128; k += 2) {
      const u32 gp = *(const u32*)(gr + k);
      const float x0 = bf2f((u16)(gp & 0xffffu));
      const float x1 = bf2f((u16)(gp >> 16));
#pragma unroll
      for (int e = 0; e < 5; ++e)
        t[e] += x0 * sgw[k * 5 + e] + x1 * sgw[(k + 1) * 5 + e];
    }
    float m = t[0];
#pragma unroll
    for (int e = 1; e < 5; ++e) m = fmaxf(m, t[e]);
    float ssum = 0.f;
#pragma unroll
    for (int e = 0; e < 5; ++e) { t[e] = expf(t[e] - m); ssum += t[e]; }
    const float inv = 1.f / ssum;
#pragma unroll
    for (int e = 0; e < 5; ++e) som[tid * 5 + e] = t[e] * inv;
  }

  for (int t = 0; t < nt; ++t) {
    const int cur = t & 1;
    barrier_nodrain();                   // WAR: buf[cur^1] free / syncs prologue
    if (t + 1 < nt) {
      stage(cur ^ 1, (t + 1) * 32);
      asm volatile("s_waitcnt vmcnt(7)" ::: "memory");   // tile t landed
    } else {
      asm volatile("s_waitcnt vmcnt(0)" ::: "memory");
    }
    barrier_nodrain();                   // all waves' tile-t DMAs visible

    short8 a[4];
#pragma unroll
    for (int i = 0; i < 4; ++i) {
      const int r = wm + i * 16 + lrow;
      a[i] = *(const short8*)(sA[cur] + r * 32 + swz(r, lq) * 8);
    }
    const int rb0 = wn + lrow, rb1 = rb0 + 16;
    const int ob0 = rb0 * 32 + swz(rb0, lq) * 8;
    const int ob1 = rb1 * 32 + swz(rb1, lq) * 8;
    __builtin_amdgcn_s_setprio(1);
#pragma unroll
    for (int e = 0; e < 5; ++e) {
      short8 b0 = *(const short8*)(sW[cur] + e * 2048 + ob0);
      short8 b1 = *(const short8*)(sW[cur] + e * 2048 + ob1);
#pragma unroll
      for (int mi = 0; mi < 4; ++mi) {
        acc[e][mi][0] = __builtin_amdgcn_mfma_f32_16x16x32_bf16(a[mi], b0, acc[e][mi][0], 0, 0, 0);
        acc[e][mi][1] = __builtin_amdgcn_mfma_f32_16x16x32_bf16(a[mi], b1, acc[e][mi][1], 0, 0, 0);
      }
    }
    __builtin_amdgcn_s_setprio(0);
  }

#pragma unroll
  for (int mi = 0; mi < 4; ++mi) {
#pragma unroll
    for (int r = 0; r < 4; ++r) {
      const int rl = wm + mi * 16 + lq * 4 + r;       // row in block tile
      const int row = bm * 128 + rl;
      float om[5];
#pragma unroll
      for (int e = 0; e < 5; ++e) om[e] = som[rl * 5 + e];
#pragma unroll
      for (int ni = 0; ni < 2; ++ni) {
        const int c = wn + ni * 16 + lrow;            // col in block tile
        const int col = bn * 64 + c;
        if (col < n_store) {
          float v = 0.f;
#pragma unroll
          for (int e = 0; e < 5; ++e) v += om[e] * (acc[e][mi][ni][r] + sbias[e][c]);
          if (ELU) v = elu_f(v);
          const size_t idx = (size_t)row * ldc + col_off + col;
          if (f32out) ((float*)C)[idx] = v;
          else        ((u16*)C)[idx]   = f2bf(v);
        }
      }
    }
  }
}

// ---------------------------------------------------------------------------
extern "C" void kernel_launch(void* const* d_in, const int* in_sizes, int n_in,
                              void* d_out, int out_size, void* d_ws, size_t ws_size,
                              hipStream_t stream)
{
  const void* z    = d_in[0];
  const void* pprev= d_in[1];
  const void* I    = d_in[2];
  const void* gw1  = d_in[3];
  const void* gb1  = d_in[4];
  const void* gw2  = d_in[5];
  const void* gb2  = d_in[6];
  const void* gw3  = d_in[7];
  const void* gb3  = d_in[8];
  const void* iw1  = d_in[9];
  const void* ib1  = d_in[10];
  const void* iw2  = d_in[11];
  const void* ib2  = d_in[12];
  const void* iw3  = d_in[13];
  const void* ib3  = d_in[14];
  const void* wl1  = d_in[15];
  const void* bl1  = d_in[16];
  const void* wl2  = d_in[17];
  const void* bl2  = d_in[18];
  const void* wl3  = d_in[19];
  const void* bl3  = d_in[20];

  char* base = (char*)d_ws;
  size_t off = 0;
  auto alloc = [&](size_t bytes) -> void* {
    void* p = base + off;
    off = (off + bytes + 255) & ~(size_t)255;
    return p;
  };

  const size_t B = BATCH;
  int* flagp   = (int*)alloc(256);
  u16* h0      = (u16*)alloc(B * 832 * 2);   // [z | p_prev | ienc | pad0]
  u16* h1c     = (u16*)alloc(B * 288 * 2);   // [z | h1]
  u16* h2c     = (u16*)alloc(B * 288 * 2);   // [z | h2]
  u16* i1      = (u16*)alloc(B * 256 * 2);
  u16* i2      = (u16*)alloc(B * 256 * 2);
  u16* g1      = (u16*)alloc(B * 256 * 2);
  u16* g2      = (u16*)alloc(B * 128 * 2);
  u16* Ibf     = (u16*)alloc(B * 2048 * 2);  // used only when storage is f32
  u16* smallc  = (u16*)alloc(7100 * 2);
  u16* iw1t = (u16*)alloc((size_t)256 * 2048 * 2);
  u16* iw2t = (u16*)alloc((size_t)256 * 256 * 2);
  u16* iw3t = (u16*)alloc((size_t)256 * 256 * 2);
  u16* gw1t = (u16*)alloc((size_t)256 * 576 * 2);
  u16* gw2t = (u16*)alloc((size_t)128 * 256 * 2);
  u16* wl1t = (u16*)alloc((size_t)5 * 256 * 832 * 2);
  u16* wl2t = (u16*)alloc((size_t)5 * 256 * 288 * 2);
  u16* wl3t = (u16*)alloc((size_t)5 * 576 * 288 * 2);
  (void)in_sizes; (void)n_in; (void)out_size; (void)ws_size;

  u16* ib1c = smallc + 0,   *ib2c = smallc + 256, *ib3c = smallc + 512;
  u16* gb1c = smallc + 768, *gb2c = smallc + 1024, *gb3c = smallc + 1152;
  u16* gw3c = smallc + 1280;
  u16* bl1c = smallc + 1920, *bl2c = smallc + 3200, *bl3c = smallc + 4480;

  // ---- fused prep: detect + canonicalize + (convert iff f32) + h-build +
  //      transpose ----
  prep_all<<<2048, 256, 0, stream>>>(z, pprev, I, flagp, h0, h1c, h2c, Ibf,
      ib1, ib2, ib3, gb1, gb2, gb3, gw3, bl1, bl2, bl3, smallc,
      iw1, iw2, iw3, gw1, gw2, wl1, wl2, wl3,
      iw1t, iw2t, iw3t, gw1t, gw2t, wl1t, wl2t, wl3t);

  // ---- small GEMMs (r9 gemm64m form, 4 blocks/CU): INet || gating ----
  GemmDesc inet1 = { (const u16*)I, Ibf, iw1t, ib1c, i1, 2048, 2048, 256, 0,   2048, 2, 1 };
  GemmDesc gat1  = { h0, h0, gw1t, gb1c, g1,  832,  576, 256, 0,    576, 2, 0 };
  GemmDesc inet2 = { i1, i1, iw2t, ib2c, i2,  256,  256, 256, 0,    256, 2, 0 };
  GemmDesc gat2  = { g1, g1, gw2t, gb2c, g2,  256,  256, 128, 0,    256, 1, 0 };
  GemmDesc inet3 = { i2, i2, iw3t, ib3c, h0,  256,  256, 832, 556,  256, 2, 0 };

  gemm64m<<<dim3(BATCH/64, 4), 256, 0, stream>>>(inet1, gat1, flagp);
  gemm64m<<<dim3(BATCH/64, 3), 256, 0, stream>>>(inet2, gat2, flagp);
  gemm64m<<<dim3(BATCH/64, 2), 256, 0, stream>>>(inet3, inet3, flagp);

  // ---- MoE layers (block 128x64, depth-1 counted-vmcnt, omega in-block) ----
  moe_gemm<true><<<dim3(BATCH/128, 4), 256, 0, stream>>>(
      h0, 832, wl1t, 832, (long)256 * 832, bl1c, 256, g2, gw3c, gb3c,
      h1c, 288, 32, 256, 832, flagp, 0);
  moe_gemm<true><<<dim3(BATCH/128, 4), 256, 0, stream>>>(
      h1c, 288, wl2t, 288, (long)256 * 288, bl2c, 256, g2, gw3c, gb3c,
      h2c, 288, 32, 256, 288, flagp, 0);
  moe_gemm<false><<<dim3(BATCH/128, 9), 256, 0, stream>>>(
      h2c, 288, wl3t, 288, (long)576 * 288, bl3c, 524, g2, gw3c, gb3c,
      d_out, 524, 0, 524, 288, flagp, 1);
}

// Round 9
// 509.364 us; speedup vs baseline: 1.0411x; 1.0153x over previous
//
#include <hip/hip_runtime.h>
#include <hip/hip_bf16.h>
#include <cstdint>
#include <cstddef>

// MotionNet decoder: B=16384, STATE=524, IENC=256, ZD=32, H=256, E=5, HG=256
// Round 15: prep_all latency fix. r14 counters: WRITE=100MB proves storage
// is FP32 (convert runs); prep 105us @ 28% HBM, VALU 9.6% = latency-bound.
// Cause: transpose reads are column-reads of row-major weights (consecutive
// lanes 4KB apart, 4 scattered dwords/item). Fix: LDS-tiled transpose, one
// 32x32 tile per wave ([32][33] private tile, coalesced reads AND writes);
// convert widened to 16 elems/item (4 indep float4 loads); phase loops
// split. gemm64m/moe_gemm/launches byte-identical to r14 (validated).

#define BATCH 16384

typedef __attribute__((ext_vector_type(8))) short short8;  // 8 bf16 (4 VGPRs)
typedef __attribute__((ext_vector_type(4))) float f32x4;   // MFMA accumulator
typedef unsigned short u16;
typedef unsigned int u32;

typedef __attribute__((address_space(3))) void lds_t;
typedef __attribute__((address_space(1))) void gmem_t;

// async global->LDS DMA, 16 B/lane. LDS dest = wave-uniform base + lane*16.
__device__ __forceinline__ void gload16(const u16* g, u16* l) {
  __builtin_amdgcn_global_load_lds((gmem_t*)(u16*)g, (lds_t*)l, 16, 0, 0);
}

// raw workgroup barrier (no counter drain)
__device__ __forceinline__ void barrier_nodrain() {
  asm volatile("" ::: "memory");
  __builtin_amdgcn_s_barrier();
  asm volatile("" ::: "memory");
}
// barrier draining LDS ops only — vmcnt stays in flight
__device__ __forceinline__ void barrier_lds() {
  asm volatile("s_waitcnt lgkmcnt(0)" ::: "memory");
  __builtin_amdgcn_s_barrier();
  asm volatile("" ::: "memory");
}

__device__ __forceinline__ float bf2f(u16 u) {
  union { float f; u32 i; } v; v.i = ((u32)u) << 16; return v.f;
}
__device__ __forceinline__ u16 f2bf(float f) {
  union { float f; u32 i; } v; v.f = f;
  u32 x = v.i;
  return (u16)((x + 0x7fffu + ((x >> 16) & 1u)) >> 16);  // RNE
}
__device__ __forceinline__ u16 load_bf(const void* p, long i, int f32) {
  return f32 ? f2bf(((const float*)p)[i]) : ((const u16*)p)[i];
}
__device__ __forceinline__ float elu_f(float x) { return x > 0.f ? x : expm1f(x); }

// LDS tile layout (validated round 4): rows of 32 u16 (64 B); 16B chunk q of
// row r lives at chunk slot q^((r>>1)&3). Staging lane l covers global chunk
// (l&3)^((l>>3)&3) of row seg+(l>>2); 16B lands at base + l*16B = correct.
__device__ __forceinline__ int swz(int row, int q) { return q ^ ((row >> 1) & 3); }

// ---------------------------------------------------------------------------
// prep_all: fused {dtype detect (per-block), smallc canonicalize (block 0),
//   I->bf16 convert (f32 only, 16 elems/item), h0/h1c/h2c build (8 cols),
//   LDS-tiled weight transposes (32x32 tile/wave, coalesced both sides)}.
// h0 cols 556..831 zeroed (gat1 reads h0[:,0:576] before inet3 fills 556..).
// ---------------------------------------------------------------------------
__global__ __launch_bounds__(256) void prep_all(
    const void* __restrict__ z, const void* __restrict__ p,
    const void* __restrict__ I, int* __restrict__ flagp,
    u16* __restrict__ h0, u16* __restrict__ h1c, u16* __restrict__ h2c,
    u16* __restrict__ Ibf,
    const void* ib1, const void* ib2, const void* ib3,
    const void* gb1, const void* gb2, const void* gb3,
    const void* gw3, const void* bl1, const void* bl2, const void* bl3,
    u16* __restrict__ smallc,
    const void* s0, const void* s1, const void* s2, const void* s3,
    const void* s4, const void* s5, const void* s6, const void* s7,
    u16* d0, u16* d1, u16* d2, u16* d3, u16* d4, u16* d5, u16* d6, u16* d7)
{
  // ---- per-block dtype detection ----
  __shared__ int scnt[4];
  __shared__ u16 tl[4][32][33];   // per-wave transpose tiles
  {
    u32 w = ((const u32*)z)[threadIdx.x];
    int e = (w >> 7) & 0xFF;
    unsigned long long m = __ballot(e >= 112 && e <= 142);
    if ((threadIdx.x & 63) == 0) scnt[threadIdx.x >> 6] = __popcll(m);
  }
  __syncthreads();
  const int f32 = (scnt[0] + scnt[1] + scnt[2] + scnt[3] < 128) ? 1 : 0;
  if (blockIdx.x == 0 && threadIdx.x == 0) *flagp = f32;

  // ---- block 0: small-tensor canonicalize ----
  if (blockIdx.x == 0) {
    for (long j = threadIdx.x; j < 7100; j += 256) {
      u16 v;
      if      (j < 256)  v = load_bf(ib1, j,        f32);
      else if (j < 512)  v = load_bf(ib2, j - 256,  f32);
      else if (j < 768)  v = load_bf(ib3, j - 512,  f32);
      else if (j < 1024) v = load_bf(gb1, j - 768,  f32);
      else if (j < 1152) v = load_bf(gb2, j - 1024, f32);
      else if (j < 1280) v = (j - 1152 < 5) ? load_bf(gb3, j - 1152, f32) : (u16)0;
      else if (j < 1920) v = load_bf(gw3, j - 1280, f32);
      else if (j < 3200) v = load_bf(bl1, j - 1920, f32);
      else if (j < 4480) v = load_bf(bl2, j - 3200, f32);
      else               v = load_bf(bl3, j - 4480, f32);
      smallc[j] = v;
    }
  }

  const long gid = (long)blockIdx.x * 256 + threadIdx.x;
  const long stride = (long)gridDim.x * 256;

  // ---- phase 1: I -> bf16 convert (only when f32 storage), 16 elems/item --
  if (f32) {
    const long NCt = (long)BATCH * 2048 / 16;
    for (long it = gid; it < NCt; it += stride) {
      const float4* sI = (const float4*)I + it * 4;
      const float4 a = sI[0], b = sI[1], c4 = sI[2], d4 = sI[3];
      uint4 w0, w1;
      w0.x = (u32)f2bf(a.x)  | ((u32)f2bf(a.y)  << 16);
      w0.y = (u32)f2bf(a.z)  | ((u32)f2bf(a.w)  << 16);
      w0.z = (u32)f2bf(b.x)  | ((u32)f2bf(b.y)  << 16);
      w0.w = (u32)f2bf(b.z)  | ((u32)f2bf(b.w)  << 16);
      w1.x = (u32)f2bf(c4.x) | ((u32)f2bf(c4.y) << 16);
      w1.y = (u32)f2bf(c4.z) | ((u32)f2bf(c4.w) << 16);
      w1.z = (u32)f2bf(d4.x) | ((u32)f2bf(d4.y) << 16);
      w1.w = (u32)f2bf(d4.z) | ((u32)f2bf(d4.w) << 16);
      *(uint4*)(Ibf + it * 16)     = w0;
      *(uint4*)(Ibf + it * 16 + 8) = w1;
    }
  }

  // ---- phase 2: h0/h1c/h2c build, 8 cols/item ----
  {
    const long NP = (long)BATCH * 104;
    for (long it = gid; it < NP; it += stride) {
      const int b = (int)(it / 104);
      const int c = (int)(it % 104) * 8;
      uint4 w; w.x = 0; w.y = 0; w.z = 0; w.w = 0;
      if (c < 32) {
        if (f32) {
          const float4 f0 = *(const float4*)((const float*)z + (long)b * 32 + c);
          const float4 f1 = *(const float4*)((const float*)z + (long)b * 32 + c + 4);
          w.x = (u32)f2bf(f0.x) | ((u32)f2bf(f0.y) << 16);
          w.y = (u32)f2bf(f0.z) | ((u32)f2bf(f0.w) << 16);
          w.z = (u32)f2bf(f1.x) | ((u32)f2bf(f1.y) << 16);
          w.w = (u32)f2bf(f1.z) | ((u32)f2bf(f1.w) << 16);
        } else {
          w = *(const uint4*)((const u16*)z + (long)b * 32 + c);
        }
        *(uint4*)(h0 + (long)b * 832 + c) = w;
        *(uint4*)(h1c + (long)b * 288 + c) = w;
        *(uint4*)(h2c + (long)b * 288 + c) = w;
        continue;
      }
      if (c < 552) {
        const long pi = (long)b * 524 + (c - 32);
        if (f32) {
          const float4 f0 = *(const float4*)((const float*)p + pi);
          const float4 f1 = *(const float4*)((const float*)p + pi + 4);
          w.x = (u32)f2bf(f0.x) | ((u32)f2bf(f0.y) << 16);
          w.y = (u32)f2bf(f0.z) | ((u32)f2bf(f0.w) << 16);
          w.z = (u32)f2bf(f1.x) | ((u32)f2bf(f1.y) << 16);
          w.w = (u32)f2bf(f1.z) | ((u32)f2bf(f1.w) << 16);
        } else {
          const uint2 a0 = *(const uint2*)((const u16*)p + pi);
          const uint2 a1 = *(const uint2*)((const u16*)p + pi + 4);
          w.x = a0.x; w.y = a0.y; w.z = a1.x; w.w = a1.y;
        }
      } else if (c == 552) {
        const long pi = (long)b * 524 + 520;   // cols 552..555; 556..559 = 0
        if (f32) {
          const float4 f0 = *(const float4*)((const float*)p + pi);
          w.x = (u32)f2bf(f0.x) | ((u32)f2bf(f0.y) << 16);
          w.y = (u32)f2bf(f0.z) | ((u32)f2bf(f0.w) << 16);
        } else {
          const uint2 a0 = *(const uint2*)((const u16*)p + pi);
          w.x = a0.x; w.y = a0.y;
        }
      }
      *(uint4*)(h0 + (long)b * 832 + c) = w;
    }
  }

  // ---- phase 3: weight transposes, one 32x32 tile per WAVE ----
  // dst[e][n][k] = src[e][k][n] (zeros in padding). Read pass: coalesced
  // rows of src; write pass: coalesced rows of dst via the LDS tile.
  {
    const void* const srcs[8] = { s0, s1, s2, s3, s4, s5, s6, s7 };
    u16* const dsts[8] = { d0, d1, d2, d3, d4, d5, d6, d7 };
    const int tKp[8] = { 2048, 256, 256, 576, 256, 832, 288, 288 };
    const int tNp[8] = {  256, 256, 256, 256, 128, 256, 256, 576 };
    const int tK [8] = { 2048, 256, 256, 556, 256, 812, 288, 288 };
    const int tN [8] = {  256, 256, 256, 256, 128, 256, 256, 524 };
    // tiles/seg: 512,64,64,144,32,1040,360,810 ; cumulative below
    const int wave = threadIdx.x >> 6, lane = threadIdx.x & 63;
    const int rl = lane >> 3;          // 0..7
    const int cl = (lane & 7) * 4;     // 0,4,..,28

    for (int t = blockIdx.x * 4 + wave; t < 3026; t += gridDim.x * 4) {
      int s, base;
      if      (t < 512)  { s = 0; base = 0; }
      else if (t < 576)  { s = 1; base = 512; }
      else if (t < 640)  { s = 2; base = 576; }
      else if (t < 784)  { s = 3; base = 640; }
      else if (t < 816)  { s = 4; base = 784; }
      else if (t < 1856) { s = 5; base = 816; }
      else if (t < 2216) { s = 6; base = 1856; }
      else               { s = 7; base = 2216; }
      const int tt = t - base;
      const int Kp = tKp[s], Np = tNp[s], K = tK[s], N = tN[s];
      const int Ktl = Kp >> 5;
      const int kt  = tt % Ktl;
      const int r2  = tt / Ktl;
      const int ntb = r2 % (Np >> 5);
      const int e   = r2 / (Np >> 5);
      const void* src = srcs[s];
      u16* dst = dsts[s];
      const long ebase = (long)e * K * N;

      // read pass: 4 sub-rows of 32 n-contiguous elems each
#pragma unroll
      for (int j = 0; j < 4; ++j) {
        const int kr = kt * 32 + rl + 8 * j;
        const int nc = ntb * 32 + cl;
        ushort4 v; v.x = 0; v.y = 0; v.z = 0; v.w = 0;
        if (kr < K) {
          const long sb = ebase + (long)kr * N + nc;
          if (nc + 3 < N) {
            if (f32) {
              const float4 f = *(const float4*)((const float*)src + sb);
              v.x = f2bf(f.x); v.y = f2bf(f.y); v.z = f2bf(f.z); v.w = f2bf(f.w);
            } else {
              v = *(const ushort4*)((const u16*)src + sb);
            }
          } else {
            if (nc     < N) v.x = load_bf(src, sb,     f32);
            if (nc + 1 < N) v.y = load_bf(src, sb + 1, f32);
            if (nc + 2 < N) v.z = load_bf(src, sb + 2, f32);
            if (nc + 3 < N) v.w = load_bf(src, sb + 3, f32);
          }
        }
        tl[wave][rl + 8 * j][cl + 0] = v.x;
        tl[wave][rl + 8 * j][cl + 1] = v.y;
        tl[wave][rl + 8 * j][cl + 2] = v.z;
        tl[wave][rl + 8 * j][cl + 3] = v.w;
      }
      // write pass: 4 sub-rows of 32 k-contiguous elems (transposed read)
#pragma unroll
      for (int j = 0; j < 4; ++j) {
        const int nr = ntb * 32 + rl + 8 * j;
        const int kc = kt * 32 + cl;
        ushort4 v;
        v.x = tl[wave][cl + 0][rl + 8 * j];
        v.y = tl[wave][cl + 1][rl + 8 * j];
        v.z = tl[wave][cl + 2][rl + 8 * j];
        v.w = tl[wave][cl + 3][rl + 8 * j];
        *(ushort4*)(dst + (long)e * Np * Kp + (long)nr * Kp + kc) = v;
      }
    }
  }
}

// ---------------------------------------------------------------------------
// Multi-segment GEMM (r9-validated form): C = elu(A @ W + bias), W [N][K].
// Block 64x128, 4 waves 2(M)x2(N), wave tile 32x64 = 2x4 MFMA 16x16x32.
// 3 LDS buffers (36 KB), depth-2 counted-vmcnt pipeline:
//   barrier -> stage(t+2) -> s_waitcnt vmcnt(6) -> barrier -> ds_read+MFMA
// __launch_bounds__(256,4): 36KB LDS + ~88 VGPR -> 4 blocks/CU (16 waves).
// A pointer selected on-device: a_mode && *flagp -> Aalt (prep-converted).
// ---------------------------------------------------------------------------
struct GemmDesc {
  const u16* A; const u16* Aalt; const u16* Wt; const u16* bias; u16* C;
  int lda, ldw, ldc, col_off, K, ny, a_mode;
};

__global__ __launch_bounds__(256, 4) void gemm64m(GemmDesc da, GemmDesc db,
                                                  const int* __restrict__ flagp)
{
  __shared__ __align__(16) u16 sA[3][64 * 32];    // 4 KB each
  __shared__ __align__(16) u16 sB[3][128 * 32];   // 8 KB each

  int bn = blockIdx.y;
  GemmDesc d;
  if (bn < da.ny) { d = da; } else { bn -= da.ny; d = db; }
  const u16* Abase = (d.a_mode && *flagp) ? d.Aalt : d.A;

  const int tid  = threadIdx.x;
  const int bm   = blockIdx.x;
  const int lane = tid & 63, wave = tid >> 6;
  const int wm = (wave & 1) * 32, wn = (wave >> 1) * 64;
  const int lrow = lane & 15, lq = lane >> 4;

  // staging: A rows 16/wave (1 DMA), B rows 32/wave (2 DMAs)
  const int sq    = (lane & 3) ^ ((lane >> 3) & 3);
  const int srowA = 16 * wave + (lane >> 2);
  const int srowB = 32 * wave + (lane >> 2);
  const u16* Ag = Abase + (size_t)(bm * 64  + srowA) * d.lda + sq * 8;
  const u16* Wg = d.Wt  + (size_t)(bn * 128 + srowB) * d.ldw + sq * 8;
  const int laOff = wave * 512;    // 16 rows * 32 u16
  const int lbOff = wave * 1024;   // 32 rows * 32 u16
  const int ldw = d.ldw;

  f32x4 acc[2][4] = {};
  const int nt = d.K / 32;

  // prologue: stage tiles 0 and 1 (no drain — loop's vmcnt covers)
  gload16(Ag, sA[0] + laOff);
  gload16(Wg, sB[0] + lbOff);
  gload16(Wg + (size_t)16 * ldw, sB[0] + lbOff + 512);
  gload16(Ag + 32, sA[1] + laOff);
  gload16(Wg + 32, sB[1] + lbOff);
  gload16(Wg + (size_t)16 * ldw + 32, sB[1] + lbOff + 512);

  for (int t = 0; t < nt; ++t) {
    const int cur = t % 3;
    barrier_nodrain();                       // WAR: slot (t+2)%3 free
    if (t + 2 < nt) {
      const int nb = (t + 2) % 3;
      const int k0 = (t + 2) * 32;
      gload16(Ag + k0, sA[nb] + laOff);
      gload16(Wg + k0, sB[nb] + lbOff);
      gload16(Wg + (size_t)16 * ldw + k0, sB[nb] + lbOff + 512);
    }
    const int ahead = nt - 1 - t;
    if (ahead >= 2)      asm volatile("s_waitcnt vmcnt(6)" ::: "memory");
    else if (ahead == 1) asm volatile("s_waitcnt vmcnt(3)" ::: "memory");
    else                 asm volatile("s_waitcnt vmcnt(0)" ::: "memory");
    barrier_nodrain();                       // all waves' tile-t DMAs visible

    short8 a[2], b[4];
#pragma unroll
    for (int i = 0; i < 2; ++i) {
      const int r = wm + i * 16 + lrow;
      a[i] = *(const short8*)(sA[cur] + r * 32 + swz(r, lq) * 8);
    }
#pragma unroll
    for (int i = 0; i < 4; ++i) {
      const int r = wn + i * 16 + lrow;
      b[i] = *(const short8*)(sB[cur] + r * 32 + swz(r, lq) * 8);
    }

    __builtin_amdgcn_s_setprio(1);
#pragma unroll
    for (int mi = 0; mi < 2; ++mi)
#pragma unroll
      for (int ni = 0; ni < 4; ++ni)
        acc[mi][ni] = __builtin_amdgcn_mfma_f32_16x16x32_bf16(a[mi], b[ni], acc[mi][ni], 0, 0, 0);
    __builtin_amdgcn_s_setprio(0);
  }

#pragma unroll
  for (int ni = 0; ni < 4; ++ni) {
    const int col = bn * 128 + wn + ni * 16 + lrow;
    const float bv = bf2f(d.bias[col]);
#pragma unroll
    for (int mi = 0; mi < 2; ++mi) {
#pragma unroll
      for (int r = 0; r < 4; ++r) {
        const int row = bm * 64 + wm + mi * 16 + lq * 4 + r;
        float v = acc[mi][ni][r] + bv;
        v = elu_f(v);
        d.C[(size_t)row * d.ldc + d.col_off + col] = f2bf(v);
      }
    }
  }
}

// ---------------------------------------------------------------------------
// MoE GEMM (r9 form, validated): out = act( sum_e om[b,e]*((A@W_e)+b_e) )
// 256 thr, block 128x64, wave tile 64x32, acc[5][4][2]; depth-1 counted-vmcnt
// (2 buffers, 56KB, 2 blocks/CU). Gating layer-3 + softmax fused in prologue.
// ---------------------------------------------------------------------------
template<bool ELU>
__global__ __launch_bounds__(256, 2) void moe_gemm(
    const u16* __restrict__ A, int lda,
    const u16* __restrict__ Wt, int ldw, long wstride_e,
    const u16* __restrict__ bias, int bias_n,
    const u16* __restrict__ g2, const u16* __restrict__ gw3c,
    const u16* __restrict__ gb3c,
    void* __restrict__ C, int ldc, int col_off, int n_store, int K,
    const int* __restrict__ flagp, int is_final)
{
  __shared__ __align__(16) u16 sA[2][128 * 32];     // 8 KB each
  __shared__ __align__(16) u16 sW[2][5 * 64 * 32];  // 20 KB each
  __shared__ float som[128 * 5];
  __shared__ float sbias[5][64];
  __shared__ float sgw[128 * 5];
  __shared__ float sgb[5];

  const int tid  = threadIdx.x;
  const int bm   = blockIdx.x, bn = blockIdx.y;
  const int lane = tid & 63, wave = tid >> 6;
  const int wm = (wave & 1) * 64, wn = (wave >> 1) * 32;
  const int lrow = lane & 15, lq = lane >> 4;
  const int f32out = is_final ? *flagp : 0;

  const int sq = (lane & 3) ^ ((lane >> 3) & 3);
  const int srowA = 32 * wave + (lane >> 2);
  const int srowW = 16 * wave + (lane >> 2);
  const u16* Ag = A  + (size_t)(bm * 128 + srowA) * lda + sq * 8;
  const u16* Wg = Wt + (size_t)(bn * 64 + srowW) * ldw + sq * 8;
  const int laOff = wave * 1024;    // 32 rows * 32 u16
  const int lWoff = wave * 512;     // 16 rows * 32 u16

  auto stage = [&](int buf, int k0) {
    gload16(Ag + k0, sA[buf] + laOff);
    gload16(Ag + (size_t)16 * lda + k0, sA[buf] + laOff + 512);
#pragma unroll
    for (int e = 0; e < 5; ++e)
      gload16(Wg + e * wstride_e + k0, sW[buf] + e * 2048 + lWoff);
  };

  f32x4 acc[5][4][2] = {};
  const int nt = K / 32;

  // ---- prologue: tile-0 DMAs in flight while omega is built in-block ----
  stage(0, 0);
  for (int t2 = tid; t2 < 960; t2 += 256) {   // 640 sgw + 320 sbias
    if (t2 < 640) {
      sgw[t2] = bf2f(gw3c[t2]);
    } else {
      const int j = t2 - 640;
      const int e = j >> 6, c = j & 63;
      const int col = bn * 64 + c;
      sbias[e][c] = (col < bias_n) ? bf2f(bias[(size_t)e * bias_n + col]) : 0.f;
    }
  }
  if (tid < 5) sgb[tid] = bf2f(gb3c[tid]);
  barrier_lds();                              // sgw/sgb visible; DMAs still fly
  if (tid < 128) {
    const u16* gr = g2 + (size_t)(bm * 128 + tid) * 128;
    float t[5];
#pragma unroll
    for (int e = 0; e < 5; ++e) t[e] = sgb[e];
    for (int k = 0; k < 128; k += 2) {
      const u32 gp = *(const u32*)(gr + k);
      const float x0 = bf2f((u16)(gp & 0xffffu));
      const float x1 = bf2f((u16)(gp >> 16));
#pragma unroll
      for (int e = 0; e < 5; ++e)
        t[e] += x0 * sgw[k * 5 + e] + x1 * sgw[(k + 1) * 5 + e];
    }
    float m = t[0];
#pragma unroll
    for (int e = 1; e < 5; ++e) m = fmaxf(m, t[e]);
    float ssum = 0.f;
#pragma unroll
    for (int e = 0; e < 5; ++e) { t[e] = expf(t[e] - m); ssum += t[e]; }
    const float inv = 1.f / ssum;
#pragma unroll
    for (int e = 0; e < 5; ++e) som[tid * 5 + e] = t[e] * inv;
  }

  for (int t = 0; t < nt; ++t) {
    const int cur = t & 1;
    barrier_nodrain();                   // WAR: buf[cur^1] free / syncs prologue
    if (t + 1 < nt) {
      stage(cur ^ 1, (t + 1) * 32);
      asm volatile("s_waitcnt vmcnt(7)" ::: "memory");   // tile t landed
    } else {
      asm volatile("s_waitcnt vmcnt(0)" ::: "memory");
    }
    barrier_nodrain();                   // all waves' tile-t DMAs visible

    short8 a[4];
#pragma unroll
    for (int i = 0; i < 4; ++i) {
      const int r = wm + i * 16 + lrow;
      a[i] = *(const short8*)(sA[cur] + r * 32 + swz(r, lq) * 8);
    }
    const int rb0 = wn + lrow, rb1 = rb0 + 16;
    const int ob0 = rb0 * 32 + swz(rb0, lq) * 8;
    const int ob1 = rb1 * 32 + swz(rb1, lq) * 8;
    __builtin_amdgcn_s_setprio(1);
#pragma unroll
    for (int e = 0; e < 5; ++e) {
      short8 b0 = *(const short8*)(sW[cur] + e * 2048 + ob0);
      short8 b1 = *(const short8*)(sW[cur] + e * 2048 + ob1);
#pragma unroll
      for (int mi = 0; mi < 4; ++mi) {
        acc[e][mi][0] = __builtin_amdgcn_mfma_f32_16x16x32_bf16(a[mi], b0, acc[e][mi][0], 0, 0, 0);
        acc[e][mi][1] = __builtin_amdgcn_mfma_f32_16x16x32_bf16(a[mi], b1, acc[e][mi][1], 0, 0, 0);
      }
    }
    __builtin_amdgcn_s_setprio(0);
  }

#pragma unroll
  for (int mi = 0; mi < 4; ++mi) {
#pragma unroll
    for (int r = 0; r < 4; ++r) {
      const int rl = wm + mi * 16 + lq * 4 + r;       // row in block tile
      const int row = bm * 128 + rl;
      float om[5];
#pragma unroll
      for (int e = 0; e < 5; ++e) om[e] = som[rl * 5 + e];
#pragma unroll
      for (int ni = 0; ni < 2; ++ni) {
        const int c = wn + ni * 16 + lrow;            // col in block tile
        const int col = bn * 64 + c;
        if (col < n_store) {
          float v = 0.f;
#pragma unroll
          for (int e = 0; e < 5; ++e) v += om[e] * (acc[e][mi][ni][r] + sbias[e][c]);
          if (ELU) v = elu_f(v);
          const size_t idx = (size_t)row * ldc + col_off + col;
          if (f32out) ((float*)C)[idx] = v;
          else        ((u16*)C)[idx]   = f2bf(v);
        }
      }
    }
  }
}

// ---------------------------------------------------------------------------
extern "C" void kernel_launch(void* const* d_in, const int* in_sizes, int n_in,
                              void* d_out, int out_size, void* d_ws, size_t ws_size,
                              hipStream_t stream)
{
  const void* z    = d_in[0];
  const void* pprev= d_in[1];
  const void* I    = d_in[2];
  const void* gw1  = d_in[3];
  const void* gb1  = d_in[4];
  const void* gw2  = d_in[5];
  const void* gb2  = d_in[6];
  const void* gw3  = d_in[7];
  const void* gb3  = d_in[8];
  const void* iw1  = d_in[9];
  const void* ib1  = d_in[10];
  const void* iw2  = d_in[11];
  const void* ib2  = d_in[12];
  const void* iw3  = d_in[13];
  const void* ib3  = d_in[14];
  const void* wl1  = d_in[15];
  const void* bl1  = d_in[16];
  const void* wl2  = d_in[17];
  const void* bl2  = d_in[18];
  const void* wl3  = d_in[19];
  const void* bl3  = d_in[20];

  char* base = (char*)d_ws;
  size_t off = 0;
  auto alloc = [&](size_t bytes) -> void* {
    void* p = base + off;
    off = (off + bytes + 255) & ~(size_t)255;
    return p;
  };

  const size_t B = BATCH;
  int* flagp   = (int*)alloc(256);
  u16* h0      = (u16*)alloc(B * 832 * 2);   // [z | p_prev | ienc | pad0]
  u16* h1c     = (u16*)alloc(B * 288 * 2);   // [z | h1]
  u16* h2c     = (u16*)alloc(B * 288 * 2);   // [z | h2]
  u16* i1      = (u16*)alloc(B * 256 * 2);
  u16* i2      = (u16*)alloc(B * 256 * 2);
  u16* g1      = (u16*)alloc(B * 256 * 2);
  u16* g2      = (u16*)alloc(B * 128 * 2);
  u16* Ibf     = (u16*)alloc(B * 2048 * 2);  // used only when storage is f32
  u16* smallc  = (u16*)alloc(7100 * 2);
  u16* iw1t = (u16*)alloc((size_t)256 * 2048 * 2);
  u16* iw2t = (u16*)alloc((size_t)256 * 256 * 2);
  u16* iw3t = (u16*)alloc((size_t)256 * 256 * 2);
  u16* gw1t = (u16*)alloc((size_t)256 * 576 * 2);
  u16* gw2t = (u16*)alloc((size_t)128 * 256 * 2);
  u16* wl1t = (u16*)alloc((size_t)5 * 256 * 832 * 2);
  u16* wl2t = (u16*)alloc((size_t)5 * 256 * 288 * 2);
  u16* wl3t = (u16*)alloc((size_t)5 * 576 * 288 * 2);
  (void)in_sizes; (void)n_in; (void)out_size; (void)ws_size;

  u16* ib1c = smallc + 0,   *ib2c = smallc + 256, *ib3c = smallc + 512;
  u16* gb1c = smallc + 768, *gb2c = smallc + 1024, *gb3c = smallc + 1152;
  u16* gw3c = smallc + 1280;
  u16* bl1c = smallc + 1920, *bl2c = smallc + 3200, *bl3c = smallc + 4480;

  // ---- fused prep: detect + canonicalize + (convert iff f32) + h-build +
  //      LDS-tiled transpose ----
  prep_all<<<2048, 256, 0, stream>>>(z, pprev, I, flagp, h0, h1c, h2c, Ibf,
      ib1, ib2, ib3, gb1, gb2, gb3, gw3, bl1, bl2, bl3, smallc,
      iw1, iw2, iw3, gw1, gw2, wl1, wl2, wl3,
      iw1t, iw2t, iw3t, gw1t, gw2t, wl1t, wl2t, wl3t);

  // ---- small GEMMs (r9 gemm64m form, 4 blocks/CU): INet || gating ----
  GemmDesc inet1 = { (const u16*)I, Ibf, iw1t, ib1c, i1, 2048, 2048, 256, 0,   2048, 2, 1 };
  GemmDesc gat1  = { h0, h0, gw1t, gb1c, g1,  832,  576, 256, 0,    576, 2, 0 };
  GemmDesc inet2 = { i1, i1, iw2t, ib2c, i2,  256,  256, 256, 0,    256, 2, 0 };
  GemmDesc gat2  = { g1, g1, gw2t, gb2c, g2,  256,  256, 128, 0,    256, 1, 0 };
  GemmDesc inet3 = { i2, i2, iw3t, ib3c, h0,  256,  256, 832, 556,  256, 2, 0 };

  gemm64m<<<dim3(BATCH/64, 4), 256, 0, stream>>>(inet1, gat1, flagp);
  gemm64m<<<dim3(BATCH/64, 3), 256, 0, stream>>>(inet2, gat2, flagp);
  gemm64m<<<dim3(BATCH/64, 2), 256, 0, stream>>>(inet3, inet3, flagp);

  // ---- MoE layers (block 128x64, depth-1 counted-vmcnt, omega in-block) ----
  moe_gemm<true><<<dim3(BATCH/128, 4), 256, 0, stream>>>(
      h0, 832, wl1t, 832, (long)256 * 832, bl1c, 256, g2, gw3c, gb3c,
      h1c, 288, 32, 256, 832, flagp, 0);
  moe_gemm<true><<<dim3(BATCH/128, 4), 256, 0, stream>>>(
      h1c, 288, wl2t, 288, (long)256 * 288, bl2c, 256, g2, gw3c, gb3c,
      h2c, 288, 32, 256, 288, flagp, 0);
  moe_gemm<false><<<dim3(BATCH/128, 9), 256, 0, stream>>>(
      h2c, 288, wl3t, 288, (long)576 * 288, bl3c, 524, g2, gw3c, gb3c,
      d_out, 524, 0, 524, 288, flagp, 1);
}